// Round 3
// baseline (437.807 us; speedup 1.0000x reference)
//
#include <hip/hip_runtime.h>

// BatchSRU (L=2048,B=8,D=128,NB=16), 5-kernel pipeline:
//  k_wprep: W -> fp16 hi/lo MFMA-fragment order   [R3 fix: grid 384, was 1536 -> OOB fault]
//  k_prep : x (L,B,D,NB) fp32 -> XP[k][b][l][d] packed u32 (fp16 hi | lo<<16)
//  k_sru  : per (b,k,seg of 256 l): GEMM (3-product fp16 MFMA) + local scan,
//           h0 written IN-PLACE over XP; rP (l<64) + segment summaries out.
//           10 waves: 8 GEMM + 2 scan; counted vmcnt(1) + raw s_barrier.
//  k_comb : chain segment summaries -> Cin per (segment, channel)
//  k_fin  : h = h0 + rP*Cin, transpose back to (L,B,D,NB)

typedef float f32x4 __attribute__((ext_vector_type(4)));
typedef _Float16 f16x8 __attribute__((ext_vector_type(8)));
typedef unsigned int u32;
typedef u32 u32x4 __attribute__((ext_vector_type(4)));
typedef unsigned short u16;

__device__ inline u32 pack_hl(float x) {
  _Float16 h = (_Float16)x;
  _Float16 l = (_Float16)(x - (float)h);
  u32 uh = (u32)__builtin_bit_cast(u16, h);
  u32 ul = (u32)__builtin_bit_cast(u16, l);
  return uh | (ul << 16);
}
__device__ inline float unpack_hl(u32 v) {
  return (float)__builtin_bit_cast(_Float16, (u16)(v & 0xffffu)) +
         (float)__builtin_bit_cast(_Float16, (u16)(v >> 16));
}

// ---------------- W fragment pre-pack ----------------
// Wf idx(k,cti,w,s,lam,ii) = ((((k*3+cti)*8+w)*4+s)*64+lam)*8+ii
// value = W[k][32s + 8*(lam>>4) + ii][cti*128 + 16w + (lam&15)]
// combos (k,cti,w,s,lam) = 16*3*8*4*64 = 98304 threads = 384 blocks of 256.
__global__ __launch_bounds__(256) void k_wprep(const float* __restrict__ W,
                                               _Float16* __restrict__ Wfh,
                                               _Float16* __restrict__ Wfl) {
  int e = blockIdx.x * 256 + threadIdx.x;  // 0..98303
  int lam = e & 63;
  int t = e >> 6;
  int s = t & 3; t >>= 2;
  int w = t & 7; t >>= 3;
  int cti = t % 3;
  int k = t / 3;
  const float* Wp = W + (size_t)k * 128 * 384 + (size_t)(cti * 128 + 16 * w + (lam & 15));
  int row0 = 32 * s + 8 * (lam >> 4);
  size_t o = (size_t)e * 8;
#pragma unroll
  for (int ii = 0; ii < 8; ++ii) {
    float v = Wp[(size_t)(row0 + ii) * 384];
    _Float16 h = (_Float16)v;
    Wfh[o + ii] = h;
    Wfl[o + ii] = (_Float16)(v - (float)h);
  }
}

// ---------------- x transpose + pack ----------------
__global__ __launch_bounds__(256) void k_prep(const float* __restrict__ x,
                                              u32* __restrict__ XP) {
  __shared__ u32 S[2][16 * 193];
  const int bid = blockIdx.x;
  const int b = bid & 7, l0 = (bid >> 3) * 4;
  const int t = threadIdx.x;
  const int d0 = t >> 1, kc = t & 1;
  const int kk = t >> 4, dc = t & 15;
  const int pw = d0 + 4 * (d0 >> 3);  // gap position: p(d)=d+4*(d>>3)
  for (int li = 0; li < 4; ++li) {
    const int l = l0 + li;
    const float* src = x + ((size_t)(l * 8 + b) * 128 + d0) * 16 + kc * 8;
    f32x4 v0 = *(const f32x4*)src;
    f32x4 v1 = *(const f32x4*)(src + 4);
    u32* Sw = S[li & 1];
#pragma unroll
    for (int i = 0; i < 8; ++i) {
      float xv = (i < 4) ? v0[i] : v1[i - 4];
      Sw[(kc * 8 + i) * 193 + pw] = pack_hl(xv);
    }
    __syncthreads();
    u32 vv[8];
#pragma unroll
    for (int e = 0; e < 8; ++e) vv[e] = Sw[kk * 193 + 12 * dc + e];
    size_t o = ((size_t)(kk * 8 + b) * 2048 + l) * 128 + dc * 8;
    *(u32x4*)(XP + o) = (u32x4){vv[0], vv[1], vv[2], vv[3]};
    *(u32x4*)(XP + o + 4) = (u32x4){vv[4], vv[5], vv[6], vv[7]};
  }
}

// ---------------- fused GEMM + segmented scan ----------------
__global__ __launch_bounds__(640) void k_sru(
    u32* __restrict__ XP, const _Float16* __restrict__ Wfh,
    const _Float16* __restrict__ Wfl, const float* __restrict__ bias,
    _Float16* __restrict__ rP, float* __restrict__ Pseg,
    float* __restrict__ Cend) {
  __shared__ u32 Xp[3][16 * 128];    // staged x tiles (packed), chunk-XOR swizzled
  __shared__ u32 Ut[2][16 * 320];    // [m][ x~ f32 128 | f f32 128 | r fp16 64d ]

  const int bid = blockIdx.x;
  const int b = bid & 7, k = (bid >> 3) & 15, s = bid >> 7;
  const int tid = threadIdx.x, wl = tid & 63, w = tid >> 6;
  const size_t chanbase = (size_t)(k * 8 + b);
  const size_t rowbase = chanbase * 2048 + (size_t)s * 256;

  f16x8 BH[3][4], BL[3][4];
  float biasF = 0.f, biasR = 0.f;
  if (w < 8) {
#pragma unroll
    for (int cti = 0; cti < 3; ++cti)
#pragma unroll
      for (int s2 = 0; s2 < 4; ++s2) {
        size_t off = ((((size_t)(k * 3 + cti) * 8 + w) * 4 + s2) * 64 + wl) * 8;
        BH[cti][s2] = *(const f16x8*)(Wfh + off);
        BL[cti][s2] = *(const f16x8*)(Wfl + off);
      }
    int cx = 16 * w + (wl & 15);
    biasF = bias[k * 256 + cx];
    biasR = bias[k * 256 + 128 + cx];
  }

  auto stage = [&](int tile) {
    int nb = tile % 3;
    int r = 2 * w + (wl >> 5);
    int a = wl & 31;
    int cslot = a >> 1;
    int clog = cslot ^ (r & 7);
    int within = (a & 1) * 4;
    const u32* src = XP + (rowbase + tile * 16 + r) * 128 + clog * 8 + within;
    __builtin_amdgcn_global_load_lds(
        (const __attribute__((address_space(1))) void*)src,
        (__attribute__((address_space(3))) void*)&Xp[nb][2 * w * 128], 16, 0, 0);
  };

  auto gemm = [&](int tile) {
    const int nb = tile % 3, ub = tile & 1;
    const int n = wl & 15, g = wl >> 4;
    f32x4 a0 = {0.f, 0.f, 0.f, 0.f}, a1 = a0, a2 = a0;
#pragma unroll
    for (int s2 = 0; s2 < 4; ++s2) {
      int slot = (4 * s2 + g) ^ (n & 7);
      const u32* px = &Xp[nb][n * 128 + slot * 8];
      u32x4 q0 = *(const u32x4*)px;
      u32x4 q1 = *(const u32x4*)(px + 4);
      u32 h0 = __builtin_amdgcn_perm(q0[1], q0[0], 0x05040100u);
      u32 h1 = __builtin_amdgcn_perm(q0[3], q0[2], 0x05040100u);
      u32 h2 = __builtin_amdgcn_perm(q1[1], q1[0], 0x05040100u);
      u32 h3 = __builtin_amdgcn_perm(q1[3], q1[2], 0x05040100u);
      u32 l0 = __builtin_amdgcn_perm(q0[1], q0[0], 0x07060302u);
      u32 l1 = __builtin_amdgcn_perm(q0[3], q0[2], 0x07060302u);
      u32 l2 = __builtin_amdgcn_perm(q1[1], q1[0], 0x07060302u);
      u32 l3 = __builtin_amdgcn_perm(q1[3], q1[2], 0x07060302u);
      f16x8 ah = __builtin_bit_cast(f16x8, (u32x4){h0, h1, h2, h3});
      f16x8 al = __builtin_bit_cast(f16x8, (u32x4){l0, l1, l2, l3});
      a0 = __builtin_amdgcn_mfma_f32_16x16x32_f16(ah, BH[0][s2], a0, 0, 0, 0);
      a1 = __builtin_amdgcn_mfma_f32_16x16x32_f16(ah, BH[1][s2], a1, 0, 0, 0);
      a2 = __builtin_amdgcn_mfma_f32_16x16x32_f16(ah, BH[2][s2], a2, 0, 0, 0);
      a0 = __builtin_amdgcn_mfma_f32_16x16x32_f16(al, BH[0][s2], a0, 0, 0, 0);
      a1 = __builtin_amdgcn_mfma_f32_16x16x32_f16(al, BH[1][s2], a1, 0, 0, 0);
      a2 = __builtin_amdgcn_mfma_f32_16x16x32_f16(al, BH[2][s2], a2, 0, 0, 0);
      a0 = __builtin_amdgcn_mfma_f32_16x16x32_f16(ah, BL[0][s2], a0, 0, 0, 0);
      a1 = __builtin_amdgcn_mfma_f32_16x16x32_f16(ah, BL[1][s2], a1, 0, 0, 0);
      a2 = __builtin_amdgcn_mfma_f32_16x16x32_f16(ah, BL[2][s2], a2, 0, 0, 0);
    }
    float* Uf = (float*)Ut[ub];
    _Float16* Uh = (_Float16*)Ut[ub];
    const int cx = 16 * w + n;
#pragma unroll
    for (int e = 0; e < 4; ++e) {
      int row = 4 * g + e;
      int rot = 4 * (row & 7);
      Uf[row * 320 + ((cx + rot) & 127)] = a0[e];
      float fv = 1.f / (1.f + __expf(-(a1[e] + biasF)));
      Uf[row * 320 + 128 + ((cx + rot) & 127)] = fv;
      float rv = 1.f / (1.f + __expf(-(a2[e] + biasR)));
      Uh[(row * 320 + 256 + (((cx >> 1) + rot) & 63)) * 2 + (cx & 1)] = (_Float16)rv;
    }
  };

  float c = 0.f, P = 1.f;

  auto scan = [&](int tile) {
    const int ub = tile & 1;
    const int d = (w - 8) * 64 + wl;
    const float* Uf = (const float*)Ut[ub];
    const _Float16* Uh = (const _Float16*)Ut[ub];
    const size_t growbase = (rowbase + tile * 16) * 128 + d;
    u32 xw[16];
#pragma unroll
    for (int m = 0; m < 16; ++m) xw[m] = XP[growbase + (size_t)m * 128];
    float* H0 = (float*)XP;
    const bool storeRP = tile < 4;
#pragma unroll
    for (int m = 0; m < 16; ++m) {
      int rot = 4 * (m & 7);
      float xt = Uf[m * 320 + ((d + rot) & 127)];
      float fv = Uf[m * 320 + 128 + ((d + rot) & 127)];
      float rv = (float)Uh[(m * 320 + 256 + (((d >> 1) + rot) & 63)) * 2 + (d & 1)];
      c = xt + fv * (c - xt);
      P *= fv;
      if (storeRP)
        rP[((chanbase * 8 + s) * 64 + (tile * 16 + m)) * 128 + d] = (_Float16)(rv * P);
      float xval = unpack_hl(xw[m]);
      H0[growbase + (size_t)m * 128] = xval + rv * (c - xval);
    }
  };

  if (w < 8) { stage(0); stage(1); }
  if (w < 8) asm volatile("s_waitcnt vmcnt(1) lgkmcnt(0)" ::: "memory");
  __builtin_amdgcn_s_barrier();
  __builtin_amdgcn_sched_barrier(0);

  for (int i = 0; i < 16; ++i) {
    if (w < 8) {
      if (i < 14) stage(i + 2);
      gemm(i);
    } else {
      if (i >= 1) scan(i - 1);
    }
    __builtin_amdgcn_sched_barrier(0);
    if (w < 8) {
      if (i < 14) asm volatile("s_waitcnt vmcnt(1) lgkmcnt(0)" ::: "memory");
      else        asm volatile("s_waitcnt vmcnt(0) lgkmcnt(0)" ::: "memory");
    }
    __builtin_amdgcn_s_barrier();
    __builtin_amdgcn_sched_barrier(0);
  }

  if (w >= 8) {
    scan(15);
    int d = (w - 8) * 64 + wl;
    size_t ch = chanbase * 128 + d;
    Pseg[(size_t)s * 16384 + ch] = P;
    Cend[(size_t)s * 16384 + ch] = c;
  }
}

// ---------------- segment chain ----------------
__global__ __launch_bounds__(256) void k_comb(const float* __restrict__ Pseg,
                                              const float* __restrict__ Cend,
                                              float* __restrict__ Cin) {
  int ch = blockIdx.x * 256 + threadIdx.x;
  float c = 0.f;
#pragma unroll
  for (int s = 0; s < 8; ++s) {
    Cin[s * 16384 + ch] = c;
    c = Cend[s * 16384 + ch] + Pseg[s * 16384 + ch] * c;
  }
}

// ---------------- correction + transpose back ----------------
__global__ __launch_bounds__(256) void k_fin(const float* __restrict__ H0,
                                             const _Float16* __restrict__ rP,
                                             const float* __restrict__ Cin,
                                             float* __restrict__ out) {
  __shared__ float S[2][16 * 193];
  const int bid = blockIdx.x;
  const int b = bid & 7, l0 = (bid >> 3) * 4;
  const int t = threadIdx.x;
  const int kk = t >> 4, dc = t & 15;
  const int d0 = t >> 1, kc = t & 1;
  const int pw = d0 + 4 * (d0 >> 3);
  for (int li = 0; li < 4; ++li) {
    const int l = l0 + li;
    const int sseg = l >> 8, lloc = l & 255;
    size_t hb = ((size_t)(kk * 8 + b) * 2048 + l) * 128 + dc * 8;
    f32x4 h0a = *(const f32x4*)(H0 + hb);
    f32x4 h0b = *(const f32x4*)(H0 + hb + 4);
    if (lloc < 64) {
      size_t rb = (((size_t)(kk * 8 + b) * 8 + sseg) * 64 + lloc) * 128 + dc * 8;
      f16x8 rp8 = *(const f16x8*)(rP + rb);
      size_t cb = (size_t)sseg * 16384 + (size_t)(kk * 8 + b) * 128 + dc * 8;
      f32x4 c0 = *(const f32x4*)(Cin + cb);
      f32x4 c1 = *(const f32x4*)(Cin + cb + 4);
#pragma unroll
      for (int e = 0; e < 4; ++e) {
        h0a[e] += (float)rp8[e] * c0[e];
        h0b[e] += (float)rp8[4 + e] * c1[e];
      }
    }
    float* Sw = S[li & 1];
#pragma unroll
    for (int e = 0; e < 8; ++e)
      Sw[kk * 193 + 12 * dc + e] = (e < 4) ? h0a[e] : h0b[e - 4];
    __syncthreads();
    float ov[8];
#pragma unroll
    for (int i = 0; i < 8; ++i) ov[i] = Sw[(kc * 8 + i) * 193 + pw];
    size_t oo = ((size_t)(l * 8 + b) * 128 + d0) * 16 + kc * 8;
    *(f32x4*)(out + oo) = (f32x4){ov[0], ov[1], ov[2], ov[3]};
    *(f32x4*)(out + oo + 4) = (f32x4){ov[4], ov[5], ov[6], ov[7]};
  }
}

extern "C" void kernel_launch(void* const* d_in, const int* in_sizes, int n_in,
                              void* d_out, int out_size, void* d_ws, size_t ws_size,
                              hipStream_t stream) {
  (void)in_sizes; (void)n_in; (void)out_size; (void)ws_size;
  const float* x = (const float*)d_in[0];
  const float* W = (const float*)d_in[1];
  const float* bias = (const float*)d_in[2];
  float* out = (float*)d_out;
  char* ws = (char*)d_ws;
  u32* XP        = (u32*)ws;                          // 134,217,728 B (also h0 out)
  _Float16* Wfh  = (_Float16*)(ws + 134217728);       //   1,572,864 B
  _Float16* Wfl  = (_Float16*)(ws + 135790592);       //   1,572,864 B
  _Float16* rPp  = (_Float16*)(ws + 137363456);       //  16,777,216 B
  float* Pseg    = (float*)(ws + 154140672);          //     524,288 B
  float* Cend    = (float*)(ws + 154664960);          //     524,288 B
  float* Cin     = (float*)(ws + 155189248);          //     524,288 B (end ~148.5 MiB)

  k_wprep<<<384, 256, 0, stream>>>(W, Wfh, Wfl);
  k_prep<<<4096, 256, 0, stream>>>(x, XP);
  k_sru<<<1024, 640, 0, stream>>>(XP, Wfh, Wfl, bias, rPp, Pseg, Cend);
  k_comb<<<64, 256, 0, stream>>>(Pseg, Cend, Cin);
  k_fin<<<4096, 256, 0, stream>>>((const float*)XP, rPp, Cin, out);
}